// Round 12
// baseline (136.520 us; speedup 1.0000x reference)
//
#include <hip/hip_runtime.h>

#define SQd 4096
#define SKVd 4096
#define DDIM 64
#define BK 32                          // keys per tile
#define NG 8                           // key groups (waves) per block
#define NTILES (SKVd / BK)             // 128 tiles per batch
#define TPG (NTILES / NG)              // 16 tiles per wave
#define TILE_BYTES 2048                // per operand: 2 superfrags x 1024 B
#define KWS_BYTES (4 * NTILES * TILE_BYTES)   // 1 MB per operand
#define CROWS 32                       // q-rows per chunk (2 qg per wave)
#define NCHUNK 2                       // chunks per block (serial)

typedef float floatx4 __attribute__((ext_vector_type(4)));

__device__ inline long long mk64(int lo, int hi) {
    int2 t; t.x = lo; t.y = hi;
    return __builtin_bit_cast(long long, t);
}
// Word-select must be an immediate constant -> template parameter.
template <bool HI>
__device__ inline int pk2(float a, float b, int old) {
    return __builtin_amdgcn_cvt_pk_fp8_f32(a, b, old, HI);
}

// LDS: cross-group combine only (8 key-groups -> 4 slots, 2 rounds).
struct CombS {
    float Ored[CROWS][4][68];
    float Lred[CROWS][NG];
};

// ---------------- Pre-pass: pack K and V into fp8 MFMA superfrags ----------
// (unchanged from R8/R9 — verified correct)
__global__ __launch_bounds__(256)
void prepack_kernel(const float* __restrict__ k, const float* __restrict__ v,
                    char* __restrict__ ws)
{
    __shared__ __align__(16) float Kt[BK][68];
    __shared__ __align__(16) float Vt[BK][68];

    const int blk  = blockIdx.x;          // b*NTILES + tile
    const int b    = blk >> 7;
    const int tile = blk & (NTILES - 1);
    const int tid  = threadIdx.x;

    const size_t base = ((size_t)b * SKVd + tile * BK) * DDIM;
    {
        const int row = tid >> 3, col = (tid & 7) * 8;
        const float4 k0 = *(const float4*)(k + base + (size_t)row * DDIM + col);
        const float4 k1 = *(const float4*)(k + base + (size_t)row * DDIM + col + 4);
        *(float4*)&Kt[row][col] = k0; *(float4*)&Kt[row][col + 4] = k1;
        const float4 v0 = *(const float4*)(v + base + (size_t)row * DDIM + col);
        const float4 v1 = *(const float4*)(v + base + (size_t)row * DDIM + col + 4);
        *(float4*)&Vt[row][col] = v0; *(float4*)&Vt[row][col + 4] = v1;
    }
    __syncthreads();

    const int lane = tid & 63;
    const int l16  = lane & 15;
    const int quad = lane >> 4;
    const int f    = tid >> 6;            // 0,1: K kh; 2,3: V pair

    int w[4];
    size_t off;
    if (f < 2) {
        const float* s0 = &Kt[f * 16 + l16][quad * 8];        // dh0
        const float* s1 = &Kt[f * 16 + l16][32 + quad * 8];   // dh1
        w[0] = pk2<false>(s0[0], s0[1], 0); w[0] = pk2<true>(s0[2], s0[3], w[0]);
        w[1] = pk2<false>(s0[4], s0[5], 0); w[1] = pk2<true>(s0[6], s0[7], w[1]);
        w[2] = pk2<false>(s1[0], s1[1], 0); w[2] = pk2<true>(s1[2], s1[3], w[2]);
        w[3] = pk2<false>(s1[4], s1[5], 0); w[3] = pk2<true>(s1[6], s1[7], w[3]);
        off = ((size_t)(b * NTILES + tile) * 2 + f) * 1024 + lane * 16;
    } else {
        const int p = f - 2;
        float vv[16];
        #pragma unroll
        for (int j2 = 0; j2 < 16; ++j2) {
            const int nb = 2 * p + (j2 >> 3);
            const int j  = j2 & 7;
            vv[j2] = Vt[16 * (j >> 2) + quad * 4 + (j & 3)][nb * 16 + l16];
        }
        #pragma unroll
        for (int i = 0; i < 4; ++i) {
            w[i] = pk2<false>(vv[4 * i], vv[4 * i + 1], 0);
            w[i] = pk2<true>(vv[4 * i + 2], vv[4 * i + 3], w[i]);
        }
        off = (size_t)KWS_BYTES + ((size_t)(b * NTILES + tile) * 2 + p) * 1024 + lane * 16;
    }
    int4 o4; o4.x = w[0]; o4.y = w[1]; o4.z = w[2]; o4.w = w[3];
    *(int4*)(ws + off) = o4;
}

// ---------------- Main kernel ---------------------------------------------
// R9 inner structure, but each block serially processes NCHUNK=2 q-chunks of
// 32 rows (grid 256, 1 block/CU). Same total work; dispatch duration ~2x so
// it surfaces in the rocprof top-5 with full counters (instrumentation), and
// the Q/isf prologue + block launch cost is amortized.
__global__ __launch_bounds__(512, 4)
void fattn_kernel(const float* __restrict__ q, const int* __restrict__ isf_p,
                  const char* __restrict__ kws, const char* __restrict__ vws,
                  float* __restrict__ out)
{
    __shared__ __align__(16) CombS C;

    const int tid  = threadIdx.x;
    const int g    = tid >> 6;    // key group 0..7 (512 keys)
    const int lane = tid & 63;
    const int l16  = lane & 15;
    const int quad = lane >> 4;

    const int bidx = blockIdx.x;        // 0..255
    const int b    = bidx >> 6;         // batch
    const int qb0  = (bidx & 63) * (CROWS * NCHUNK);

    // exp(s) = 2^(s*log2e); constant -4 folded into the MFMA C-init keeps
    // p' = e^(s-4) within e4m3 range.
    const float scale = 1.44269504088896340736f / (float)(*isf_p);
    const float SINIT = -4.0f * 1.44269504088896340736f;

    const char* kg = kws + (size_t)(b * NTILES + g * TPG) * TILE_BYTES + lane * 16;
    const char* vg = vws + (size_t)(b * NTILES + g * TPG) * TILE_BYTES + lane * 16;
    const int phase = bidx & (TPG - 1);   // decorrelate L2 streams across CUs

    const floatx4 sinit = {SINIT, SINIT, SINIT, SINIT};

    for (int qc = 0; qc < NCHUNK; ++qc) {
        const int qbase = qb0 + qc * CROWS;

        long long qf[2][2];
        #pragma unroll
        for (int qg = 0; qg < 2; ++qg) {
            const int qrow = qbase + qg * 16 + l16;
            const float* qp = q + ((size_t)b * SQd + qrow) * DDIM + quad * 8;
            #pragma unroll
            for (int dh = 0; dh < 2; ++dh) {
                const float4 a0 = *(const float4*)(qp + dh * 32);
                const float4 a1 = *(const float4*)(qp + dh * 32 + 4);
                int lo = pk2<false>(a0.x * scale, a0.y * scale, 0);
                lo     = pk2<true>(a0.z * scale, a0.w * scale, lo);
                int hi = pk2<false>(a1.x * scale, a1.y * scale, 0);
                hi     = pk2<true>(a1.z * scale, a1.w * scale, hi);
                qf[qg][dh] = mk64(lo, hi);
            }
        }

        floatx4 o[2][4];
        float l_acc[2];
        #pragma unroll
        for (int qg = 0; qg < 2; ++qg) {
            l_acc[qg] = 0.0f;
            #pragma unroll
            for (int nb = 0; nb < 4; ++nb)
                #pragma unroll
                for (int r = 0; r < 4; ++r) o[qg][nb][r] = 0.0f;
        }

        auto load = [&](int4* kd, int4* vd, int t) {
            const size_t off = (size_t)((t + phase) & (TPG - 1)) * TILE_BYTES;
            kd[0] = *(const int4*)(kg + off);
            kd[1] = *(const int4*)(kg + off + 1024);
            vd[0] = *(const int4*)(vg + off);
            vd[1] = *(const int4*)(vg + off + 1024);
        };
        auto compute = [&](const int4* kc, const int4* vc) {
            const long long k00 = mk64(kc[0].x, kc[0].y), k01 = mk64(kc[0].z, kc[0].w);
            const long long k10 = mk64(kc[1].x, kc[1].y), k11 = mk64(kc[1].z, kc[1].w);
            const long long v0 = mk64(vc[0].x, vc[0].y), v1 = mk64(vc[0].z, vc[0].w);
            const long long v2 = mk64(vc[1].x, vc[1].y), v3 = mk64(vc[1].z, vc[1].w);
            #pragma unroll
            for (int qg = 0; qg < 2; ++qg) {
                floatx4 s0 = sinit, s1 = sinit;
                s0 = __builtin_amdgcn_mfma_f32_16x16x32_fp8_fp8(k00, qf[qg][0], s0, 0, 0, 0);
                s0 = __builtin_amdgcn_mfma_f32_16x16x32_fp8_fp8(k01, qf[qg][1], s0, 0, 0, 0);
                s1 = __builtin_amdgcn_mfma_f32_16x16x32_fp8_fp8(k10, qf[qg][0], s1, 0, 0, 0);
                s1 = __builtin_amdgcn_mfma_f32_16x16x32_fp8_fp8(k11, qf[qg][1], s1, 0, 0, 0);
                const float p00 = __builtin_amdgcn_exp2f(s0[0]);
                const float p01 = __builtin_amdgcn_exp2f(s0[1]);
                const float p02 = __builtin_amdgcn_exp2f(s0[2]);
                const float p03 = __builtin_amdgcn_exp2f(s0[3]);
                const float p10 = __builtin_amdgcn_exp2f(s1[0]);
                const float p11 = __builtin_amdgcn_exp2f(s1[1]);
                const float p12 = __builtin_amdgcn_exp2f(s1[2]);
                const float p13 = __builtin_amdgcn_exp2f(s1[3]);
                l_acc[qg] += (p00 + p01) + (p02 + p03) + (p10 + p11) + (p12 + p13);
                int lo = pk2<false>(p00, p01, 0); lo = pk2<true>(p02, p03, lo);
                int hi = pk2<false>(p10, p11, 0); hi = pk2<true>(p12, p13, hi);
                const long long pf = mk64(lo, hi);   // PV A-frag, sigma byte order
                o[qg][0] = __builtin_amdgcn_mfma_f32_16x16x32_fp8_fp8(pf, v0, o[qg][0], 0, 0, 0);
                o[qg][1] = __builtin_amdgcn_mfma_f32_16x16x32_fp8_fp8(pf, v1, o[qg][1], 0, 0, 0);
                o[qg][2] = __builtin_amdgcn_mfma_f32_16x16x32_fp8_fp8(pf, v2, o[qg][2], 0, 0, 0);
                o[qg][3] = __builtin_amdgcn_mfma_f32_16x16x32_fp8_fp8(pf, v3, o[qg][3], 0, 0, 0);
            }
        };

        int4 kb0[2], vb0[2], kb1[2], vb1[2];
        load(kb0, vb0, 0);
        #pragma unroll
        for (int t = 0; t < TPG / 2; ++t) {
            load(kb1, vb1, 2 * t + 1);
            compute(kb0, vb0);
            load(kb0, vb0, (2 * t + 2) & (TPG - 1));
            compute(kb1, vb1);
        }

        // Row denominators: lanes sharing l16 (across quads) hold one row.
        #pragma unroll
        for (int qg = 0; qg < 2; ++qg) {
            l_acc[qg] += __shfl_xor(l_acc[qg], 16);
            l_acc[qg] += __shfl_xor(l_acc[qg], 32);
        }

        // Protect the C overlay: previous chunk's epilogue reads must finish.
        __syncthreads();
        if (quad == 0) {
            #pragma unroll
            for (int qg = 0; qg < 2; ++qg)
                C.Lred[qg * 16 + l16][g] = l_acc[qg];
        }
        if (g < 4) {
            #pragma unroll
            for (int qg = 0; qg < 2; ++qg)
                #pragma unroll
                for (int nb = 0; nb < 4; ++nb)
                    #pragma unroll
                    for (int r = 0; r < 4; ++r)
                        C.Ored[qg * 16 + quad * 4 + r][g][nb * 16 + l16] = o[qg][nb][r];
        }
        __syncthreads();
        if (g >= 4) {
            #pragma unroll
            for (int qg = 0; qg < 2; ++qg)
                #pragma unroll
                for (int nb = 0; nb < 4; ++nb)
                    #pragma unroll
                    for (int r = 0; r < 4; ++r)
                        C.Ored[qg * 16 + quad * 4 + r][g - 4][nb * 16 + l16] += o[qg][nb][r];
        }
        __syncthreads();

        // Epilogue: out = attn@v + q; 3x { x += 2q; sigmoid; clamp }.
        {
            const int row = tid >> 4;
            const int d4  = (tid & 15) * 4;
            float l = 0.0f;
            #pragma unroll
            for (int gg = 0; gg < NG; ++gg) l += C.Lred[row][gg];
            const float rl = 1.0f / l;
            float xs[4] = {0.f, 0.f, 0.f, 0.f};
            #pragma unroll
            for (int s = 0; s < 4; ++s) {
                const float4 t4 = *(const float4*)&C.Ored[row][s][d4];
                xs[0] += t4.x; xs[1] += t4.y; xs[2] += t4.z; xs[3] += t4.w;
            }
            const size_t idx = ((size_t)b * SQd + qbase + row) * DDIM + d4;
            const float4 q4 = *(const float4*)(q + idx);
            const float qs[4] = {q4.x, q4.y, q4.z, q4.w};
            #pragma unroll
            for (int c = 0; c < 4; ++c) {
                float x = xs[c] * rl + qs[c];
                #pragma unroll
                for (int itc = 0; itc < 3; ++itc) {
                    x = x + 2.0f * qs[c];
                    x = 1.0f / (1.0f + __expf(-x));
                    x = fminf(fmaxf(x, 0.0f), 1.0f);
                }
                xs[c] = x;
            }
            const float4 r4 = {xs[0], xs[1], xs[2], xs[3]};
            *(float4*)(out + idx) = r4;
        }
    }
}

extern "C" void kernel_launch(void* const* d_in, const int* in_sizes, int n_in,
                              void* d_out, int out_size, void* d_ws, size_t ws_size,
                              hipStream_t stream) {
    const float* q = (const float*)d_in[0];
    const float* k = (const float*)d_in[1];
    const float* v = (const float*)d_in[2];
    const int* isf = (const int*)d_in[3];
    float* out = (float*)d_out;
    char* ws = (char*)d_ws;   // Kws: 1 MB, Vws: 1 MB (fp8)

    prepack_kernel<<<dim3(4 * NTILES), dim3(256), 0, stream>>>(k, v, ws);

    const int nblocks = 4 * (SQd / (CROWS * NCHUNK));  // 256 blocks x 512 thr
    fattn_kernel<<<dim3(nblocks), dim3(512), 0, stream>>>(
        q, isf, ws, ws + KWS_BYTES, out);
}

// Round 13
// 91.902 us; speedup vs baseline: 1.4855x; 1.4855x over previous
//
#include <hip/hip_runtime.h>

#define SQd 4096
#define SKVd 4096
#define DDIM 64
#define BK 32                          // keys per tile
#define NG 8                           // key groups (waves) per block
#define NTILES (SKVd / BK)             // 128 tiles per batch
#define TPG (NTILES / NG)              // 16 tiles per wave
#define TILE_BYTES 2048                // per operand: 2 superfrags x 1024 B
#define KWS_BYTES (4 * NTILES * TILE_BYTES)   // 1 MB per operand
#define CROWS 32                       // q-rows per block (2 qg per wave)

typedef float floatx4 __attribute__((ext_vector_type(4)));

__device__ inline long long mk64(int lo, int hi) {
    int2 t; t.x = lo; t.y = hi;
    return __builtin_bit_cast(long long, t);
}
// Word-select must be an immediate constant -> template parameter.
template <bool HI>
__device__ inline int pk2(float a, float b, int old) {
    return __builtin_amdgcn_cvt_pk_fp8_f32(a, b, old, HI);
}

// LDS: cross-group combine only (8 key-groups -> 4 slots, 2 rounds).
struct CombS {
    float Ored[CROWS][4][68];
    float Lred[CROWS][NG];
};

// ---------------- Pre-pass: pack K and V into fp8 MFMA superfrags ----------
// (unchanged from R8 — verified correct, ~3 us)
__global__ __launch_bounds__(256)
void prepack_kernel(const float* __restrict__ k, const float* __restrict__ v,
                    char* __restrict__ ws)
{
    __shared__ __align__(16) float Kt[BK][68];
    __shared__ __align__(16) float Vt[BK][68];

    const int blk  = blockIdx.x;          // b*NTILES + tile
    const int b    = blk >> 7;
    const int tile = blk & (NTILES - 1);
    const int tid  = threadIdx.x;

    const size_t base = ((size_t)b * SKVd + tile * BK) * DDIM;
    {
        const int row = tid >> 3, col = (tid & 7) * 8;
        const float4 k0 = *(const float4*)(k + base + (size_t)row * DDIM + col);
        const float4 k1 = *(const float4*)(k + base + (size_t)row * DDIM + col + 4);
        *(float4*)&Kt[row][col] = k0; *(float4*)&Kt[row][col + 4] = k1;
        const float4 v0 = *(const float4*)(v + base + (size_t)row * DDIM + col);
        const float4 v1 = *(const float4*)(v + base + (size_t)row * DDIM + col + 4);
        *(float4*)&Vt[row][col] = v0; *(float4*)&Vt[row][col + 4] = v1;
    }
    __syncthreads();

    const int lane = tid & 63;
    const int l16  = lane & 15;
    const int quad = lane >> 4;
    const int f    = tid >> 6;            // 0,1: K kh; 2,3: V pair

    int w[4];
    size_t off;
    if (f < 2) {
        const float* s0 = &Kt[f * 16 + l16][quad * 8];        // dh0
        const float* s1 = &Kt[f * 16 + l16][32 + quad * 8];   // dh1
        w[0] = pk2<false>(s0[0], s0[1], 0); w[0] = pk2<true>(s0[2], s0[3], w[0]);
        w[1] = pk2<false>(s0[4], s0[5], 0); w[1] = pk2<true>(s0[6], s0[7], w[1]);
        w[2] = pk2<false>(s1[0], s1[1], 0); w[2] = pk2<true>(s1[2], s1[3], w[2]);
        w[3] = pk2<false>(s1[4], s1[5], 0); w[3] = pk2<true>(s1[6], s1[7], w[3]);
        off = ((size_t)(b * NTILES + tile) * 2 + f) * 1024 + lane * 16;
    } else {
        const int p = f - 2;
        float vv[16];
        #pragma unroll
        for (int j2 = 0; j2 < 16; ++j2) {
            const int nb = 2 * p + (j2 >> 3);
            const int j  = j2 & 7;
            vv[j2] = Vt[16 * (j >> 2) + quad * 4 + (j & 3)][nb * 16 + l16];
        }
        #pragma unroll
        for (int i = 0; i < 4; ++i) {
            w[i] = pk2<false>(vv[4 * i], vv[4 * i + 1], 0);
            w[i] = pk2<true>(vv[4 * i + 2], vv[4 * i + 3], w[i]);
        }
        off = (size_t)KWS_BYTES + ((size_t)(b * NTILES + tile) * 2 + p) * 1024 + lane * 16;
    }
    int4 o4; o4.x = w[0]; o4.y = w[1]; o4.z = w[2]; o4.w = w[3];
    *(int4*)(ws + off) = o4;
}

// ---------------- Main kernel ---------------------------------------------
// R9 shape (wave = 32 q-rows x 512 keys, grid 512, 2 blocks/CU) but the
// K-loop holds ZERO local arrays/lambdas: all tile buffers, Q-frags and
// accumulators are individually named variables (macros below). R12's PMC
// showed the array+lambda version spilled to scratch (FETCH 135 MB / WRITE
// 119 MB, VGPR_Count 64) — named scalars force register allocation.

#define LOADQ(QF0, QF1, QG)                                                   \
    do {                                                                      \
        const int qrow_ = qbase + (QG) * 16 + l16;                            \
        const float* qp_ = q + ((size_t)b * SQd + qrow_) * DDIM + quad * 8;   \
        const float4 a0_ = *(const float4*)(qp_);                             \
        const float4 a1_ = *(const float4*)(qp_ + 4);                         \
        const float4 a2_ = *(const float4*)(qp_ + 32);                        \
        const float4 a3_ = *(const float4*)(qp_ + 36);                        \
        int lo_ = pk2<false>(a0_.x * scale, a0_.y * scale, 0);                \
        lo_ = pk2<true>(a0_.z * scale, a0_.w * scale, lo_);                   \
        int hi_ = pk2<false>(a1_.x * scale, a1_.y * scale, 0);                \
        hi_ = pk2<true>(a1_.z * scale, a1_.w * scale, hi_);                   \
        QF0 = mk64(lo_, hi_);                                                 \
        lo_ = pk2<false>(a2_.x * scale, a2_.y * scale, 0);                    \
        lo_ = pk2<true>(a2_.z * scale, a2_.w * scale, lo_);                   \
        hi_ = pk2<false>(a3_.x * scale, a3_.y * scale, 0);                    \
        hi_ = pk2<true>(a3_.z * scale, a3_.w * scale, hi_);                   \
        QF1 = mk64(lo_, hi_);                                                 \
    } while (0)

#define LOADT(T0, T1, T2, T3, t)                                              \
    do {                                                                      \
        const size_t off_ = (size_t)(((t) + phase) & (TPG - 1)) * TILE_BYTES; \
        T0 = *(const int4*)(kg + off_);                                       \
        T1 = *(const int4*)(kg + off_ + 1024);                                \
        T2 = *(const int4*)(vg + off_);                                       \
        T3 = *(const int4*)(vg + off_ + 1024);                                \
    } while (0)

#define QKPV(QF0, QF1, LACC, O0, O1, O2, O3)                                  \
    do {                                                                      \
        floatx4 s0 = sinit, s1 = sinit;                                       \
        s0 = __builtin_amdgcn_mfma_f32_16x16x32_fp8_fp8(k00_, QF0, s0, 0, 0, 0); \
        s0 = __builtin_amdgcn_mfma_f32_16x16x32_fp8_fp8(k01_, QF1, s0, 0, 0, 0); \
        s1 = __builtin_amdgcn_mfma_f32_16x16x32_fp8_fp8(k10_, QF0, s1, 0, 0, 0); \
        s1 = __builtin_amdgcn_mfma_f32_16x16x32_fp8_fp8(k11_, QF1, s1, 0, 0, 0); \
        const float p00 = __builtin_amdgcn_exp2f(s0[0]);                      \
        const float p01 = __builtin_amdgcn_exp2f(s0[1]);                      \
        const float p02 = __builtin_amdgcn_exp2f(s0[2]);                      \
        const float p03 = __builtin_amdgcn_exp2f(s0[3]);                      \
        const float p10 = __builtin_amdgcn_exp2f(s1[0]);                      \
        const float p11 = __builtin_amdgcn_exp2f(s1[1]);                      \
        const float p12 = __builtin_amdgcn_exp2f(s1[2]);                      \
        const float p13 = __builtin_amdgcn_exp2f(s1[3]);                      \
        LACC += (p00 + p01) + (p02 + p03) + (p10 + p11) + (p12 + p13);        \
        int lo_ = pk2<false>(p00, p01, 0); lo_ = pk2<true>(p02, p03, lo_);    \
        int hi_ = pk2<false>(p10, p11, 0); hi_ = pk2<true>(p12, p13, hi_);    \
        const long long pf_ = mk64(lo_, hi_);                                 \
        O0 = __builtin_amdgcn_mfma_f32_16x16x32_fp8_fp8(pf_, v0_, O0, 0, 0, 0); \
        O1 = __builtin_amdgcn_mfma_f32_16x16x32_fp8_fp8(pf_, v1_, O1, 0, 0, 0); \
        O2 = __builtin_amdgcn_mfma_f32_16x16x32_fp8_fp8(pf_, v2_, O2, 0, 0, 0); \
        O3 = __builtin_amdgcn_mfma_f32_16x16x32_fp8_fp8(pf_, v3_, O3, 0, 0, 0); \
    } while (0)

#define STEPC(T0, T1, T2, T3)                                                 \
    do {                                                                      \
        const long long k00_ = mk64((T0).x, (T0).y), k01_ = mk64((T0).z, (T0).w); \
        const long long k10_ = mk64((T1).x, (T1).y), k11_ = mk64((T1).z, (T1).w); \
        const long long v0_ = mk64((T2).x, (T2).y), v1_ = mk64((T2).z, (T2).w);   \
        const long long v2_ = mk64((T3).x, (T3).y), v3_ = mk64((T3).z, (T3).w);   \
        QKPV(qf00, qf01, l0, o00, o01, o02, o03);                             \
        QKPV(qf10, qf11, l1, o10, o11, o12, o13);                             \
    } while (0)

__global__ __launch_bounds__(512, 4)
void fattn_kernel(const float* __restrict__ q, const int* __restrict__ isf_p,
                  const char* __restrict__ kws, const char* __restrict__ vws,
                  float* __restrict__ out)
{
    __shared__ __align__(16) CombS C;

    const int tid  = threadIdx.x;
    const int g    = tid >> 6;    // key group 0..7 (512 keys)
    const int lane = tid & 63;
    const int l16  = lane & 15;
    const int quad = lane >> 4;

    // XCD mapping: b from low bits -> each batch's 1 MB fp8 K/V pinned to 2
    // XCDs' L2; qchunk unique per (b, bidx).
    const int bidx   = blockIdx.x;       // 0..511
    const int b      = (bidx & 7) >> 1;
    const int qchunk = ((bidx & 1) << 6) | (bidx >> 3);   // 0..127
    const int qbase  = qchunk * CROWS;
    const int phase  = (bidx >> 3) & (TPG - 1);

    // exp(s) = 2^(s*log2e); constant -4 folded into the MFMA C-init keeps
    // p' = e^(s-4) within e4m3 range.
    const float scale = 1.44269504088896340736f / (float)(*isf_p);
    const float SINIT = -4.0f * 1.44269504088896340736f;
    const floatx4 sinit = {SINIT, SINIT, SINIT, SINIT};

    long long qf00, qf01, qf10, qf11;
    LOADQ(qf00, qf01, 0);
    LOADQ(qf10, qf11, 1);

    const char* kg = kws + (size_t)(b * NTILES + g * TPG) * TILE_BYTES + lane * 16;
    const char* vg = vws + (size_t)(b * NTILES + g * TPG) * TILE_BYTES + lane * 16;

    floatx4 o00 = {0,0,0,0}, o01 = {0,0,0,0}, o02 = {0,0,0,0}, o03 = {0,0,0,0};
    floatx4 o10 = {0,0,0,0}, o11 = {0,0,0,0}, o12 = {0,0,0,0}, o13 = {0,0,0,0};
    float l0 = 0.0f, l1 = 0.0f;

    // Named double buffer A/B — nothing address-taken, pure registers.
    int4 A0, A1, A2, A3, B0, B1, B2, B3;
    LOADT(A0, A1, A2, A3, 0);
    #pragma unroll
    for (int tt = 0; tt < TPG; tt += 2) {
        LOADT(B0, B1, B2, B3, tt + 1);
        STEPC(A0, A1, A2, A3);
        LOADT(A0, A1, A2, A3, (tt + 2) & (TPG - 1));
        STEPC(B0, B1, B2, B3);
    }

    // Row denominators: lanes sharing l16 (across quads) hold one row.
    l0 += __shfl_xor(l0, 16); l0 += __shfl_xor(l0, 32);
    l1 += __shfl_xor(l1, 16); l1 += __shfl_xor(l1, 32);
    if (quad == 0) {
        C.Lred[l16][g]      = l0;
        C.Lred[16 + l16][g] = l1;
    }

    // Cross-group combine: groups 0-3 write slots, barrier, groups 4-7 add.
    if (g < 4) {
        #pragma unroll
        for (int r = 0; r < 4; ++r) {
            C.Ored[quad * 4 + r][g][l16]      = o00[r];
            C.Ored[quad * 4 + r][g][16 + l16] = o01[r];
            C.Ored[quad * 4 + r][g][32 + l16] = o02[r];
            C.Ored[quad * 4 + r][g][48 + l16] = o03[r];
            C.Ored[16 + quad * 4 + r][g][l16]      = o10[r];
            C.Ored[16 + quad * 4 + r][g][16 + l16] = o11[r];
            C.Ored[16 + quad * 4 + r][g][32 + l16] = o12[r];
            C.Ored[16 + quad * 4 + r][g][48 + l16] = o13[r];
        }
    }
    __syncthreads();
    if (g >= 4) {
        const int gs = g - 4;
        #pragma unroll
        for (int r = 0; r < 4; ++r) {
            C.Ored[quad * 4 + r][gs][l16]      += o00[r];
            C.Ored[quad * 4 + r][gs][16 + l16] += o01[r];
            C.Ored[quad * 4 + r][gs][32 + l16] += o02[r];
            C.Ored[quad * 4 + r][gs][48 + l16] += o03[r];
            C.Ored[16 + quad * 4 + r][gs][l16]      += o10[r];
            C.Ored[16 + quad * 4 + r][gs][16 + l16] += o11[r];
            C.Ored[16 + quad * 4 + r][gs][32 + l16] += o12[r];
            C.Ored[16 + quad * 4 + r][gs][48 + l16] += o13[r];
        }
    }
    __syncthreads();

    // Epilogue: out = attn@v + q; 3x { x += 2q; sigmoid; clamp }.
    {
        const int row = tid >> 4;
        const int d4  = (tid & 15) * 4;
        float l = 0.0f;
        #pragma unroll
        for (int gg = 0; gg < NG; ++gg) l += C.Lred[row][gg];
        const float rl = 1.0f / l;
        float x0 = 0.f, x1 = 0.f, x2 = 0.f, x3 = 0.f;
        #pragma unroll
        for (int s = 0; s < 4; ++s) {
            const float4 t4 = *(const float4*)&C.Ored[row][s][d4];
            x0 += t4.x; x1 += t4.y; x2 += t4.z; x3 += t4.w;
        }
        const size_t idx = ((size_t)b * SQd + qbase + row) * DDIM + d4;
        const float4 q4 = *(const float4*)(q + idx);
        float xs0 = x0 * rl + q4.x, xs1 = x1 * rl + q4.y;
        float xs2 = x2 * rl + q4.z, xs3 = x3 * rl + q4.w;
        #pragma unroll
        for (int itc = 0; itc < 3; ++itc) {
            xs0 = 1.0f / (1.0f + __expf(-(xs0 + 2.0f * q4.x)));
            xs1 = 1.0f / (1.0f + __expf(-(xs1 + 2.0f * q4.y)));
            xs2 = 1.0f / (1.0f + __expf(-(xs2 + 2.0f * q4.z)));
            xs3 = 1.0f / (1.0f + __expf(-(xs3 + 2.0f * q4.w)));
            xs0 = fminf(fmaxf(xs0, 0.0f), 1.0f);
            xs1 = fminf(fmaxf(xs1, 0.0f), 1.0f);
            xs2 = fminf(fmaxf(xs2, 0.0f), 1.0f);
            xs3 = fminf(fmaxf(xs3, 0.0f), 1.0f);
        }
        const float4 r4 = {xs0, xs1, xs2, xs3};
        *(float4*)(out + idx) = r4;
    }
}

extern "C" void kernel_launch(void* const* d_in, const int* in_sizes, int n_in,
                              void* d_out, int out_size, void* d_ws, size_t ws_size,
                              hipStream_t stream) {
    const float* q = (const float*)d_in[0];
    const float* k = (const float*)d_in[1];
    const float* v = (const float*)d_in[2];
    const int* isf = (const int*)d_in[3];
    float* out = (float*)d_out;
    char* ws = (char*)d_ws;   // Kws: 1 MB, Vws: 1 MB (fp8)

    prepack_kernel<<<dim3(4 * NTILES), dim3(256), 0, stream>>>(k, v, ws);

    const int nblocks = 4 * (SQd / CROWS);  // 512 blocks x 512 threads, 2/CU
    fattn_kernel<<<dim3(nblocks), dim3(512), 0, stream>>>(
        q, isf, ws, ws + KWS_BYTES, out);
}

// Round 14
// 91.688 us; speedup vs baseline: 1.4890x; 1.0023x over previous
//
#include <hip/hip_runtime.h>

#define SQd 4096
#define SKVd 4096
#define DDIM 64
#define BK 32                          // keys per tile
#define NG 8                           // key groups (waves) per block
#define NTILES (SKVd / BK)             // 128 tiles per batch
#define TPG (NTILES / NG)              // 16 tiles per wave
#define TILE_BYTES 2048                // per operand: 2 superfrags x 1024 B
#define KWS_BYTES (4 * NTILES * TILE_BYTES)   // 1 MB per operand
#define CROWS 32                       // q-rows per block (2 qg per wave)

typedef float floatx4 __attribute__((ext_vector_type(4)));

__device__ inline long long mk64(int lo, int hi) {
    int2 t; t.x = lo; t.y = hi;
    return __builtin_bit_cast(long long, t);
}
// Word-select must be an immediate constant -> template parameter.
template <bool HI>
__device__ inline int pk2(float a, float b, int old) {
    return __builtin_amdgcn_cvt_pk_fp8_f32(a, b, old, HI);
}

// LDS: cross-group combine only (8 key-groups -> 4 slots, 2 rounds).
struct CombS {
    float Ored[CROWS][4][68];
    float Lred[CROWS][NG];
};

// ---------------- Pre-pass: pack K and V into fp8 MFMA superfrags ----------
// (unchanged from R8 — verified correct, ~3 us)
__global__ __launch_bounds__(256)
void prepack_kernel(const float* __restrict__ k, const float* __restrict__ v,
                    char* __restrict__ ws)
{
    __shared__ __align__(16) float Kt[BK][68];
    __shared__ __align__(16) float Vt[BK][68];

    const int blk  = blockIdx.x;          // b*NTILES + tile
    const int b    = blk >> 7;
    const int tile = blk & (NTILES - 1);
    const int tid  = threadIdx.x;

    const size_t base = ((size_t)b * SKVd + tile * BK) * DDIM;
    {
        const int row = tid >> 3, col = (tid & 7) * 8;
        const float4 k0 = *(const float4*)(k + base + (size_t)row * DDIM + col);
        const float4 k1 = *(const float4*)(k + base + (size_t)row * DDIM + col + 4);
        *(float4*)&Kt[row][col] = k0; *(float4*)&Kt[row][col + 4] = k1;
        const float4 v0 = *(const float4*)(v + base + (size_t)row * DDIM + col);
        const float4 v1 = *(const float4*)(v + base + (size_t)row * DDIM + col + 4);
        *(float4*)&Vt[row][col] = v0; *(float4*)&Vt[row][col + 4] = v1;
    }
    __syncthreads();

    const int lane = tid & 63;
    const int l16  = lane & 15;
    const int quad = lane >> 4;
    const int f    = tid >> 6;            // 0,1: K kh; 2,3: V pair

    int w[4];
    size_t off;
    if (f < 2) {
        const float* s0 = &Kt[f * 16 + l16][quad * 8];        // dh0
        const float* s1 = &Kt[f * 16 + l16][32 + quad * 8];   // dh1
        w[0] = pk2<false>(s0[0], s0[1], 0); w[0] = pk2<true>(s0[2], s0[3], w[0]);
        w[1] = pk2<false>(s0[4], s0[5], 0); w[1] = pk2<true>(s0[6], s0[7], w[1]);
        w[2] = pk2<false>(s1[0], s1[1], 0); w[2] = pk2<true>(s1[2], s1[3], w[2]);
        w[3] = pk2<false>(s1[4], s1[5], 0); w[3] = pk2<true>(s1[6], s1[7], w[3]);
        off = ((size_t)(b * NTILES + tile) * 2 + f) * 1024 + lane * 16;
    } else {
        const int p = f - 2;
        float vv[16];
        #pragma unroll
        for (int j2 = 0; j2 < 16; ++j2) {
            const int nb = 2 * p + (j2 >> 3);
            const int j  = j2 & 7;
            vv[j2] = Vt[16 * (j >> 2) + quad * 4 + (j & 3)][nb * 16 + l16];
        }
        #pragma unroll
        for (int i = 0; i < 4; ++i) {
            w[i] = pk2<false>(vv[4 * i], vv[4 * i + 1], 0);
            w[i] = pk2<true>(vv[4 * i + 2], vv[4 * i + 3], w[i]);
        }
        off = (size_t)KWS_BYTES + ((size_t)(b * NTILES + tile) * 2 + p) * 1024 + lane * 16;
    }
    int4 o4; o4.x = w[0]; o4.y = w[1]; o4.z = w[2]; o4.w = w[3];
    *(int4*)(ws + off) = o4;
}

// ---------------- Main kernel ---------------------------------------------
// R13 body (zero address-taken aggregates in the K-loop) but at
// __launch_bounds__(512, 2): VGPR cap 256 so the ~140 live registers fit with
// NO spill. R13's (512,4)=128 cap forced residual spilling (live count ~125 +
// tuple-alignment fragmentation); R8-R12 spilled via address-taken arrays
// (R12 PMC: VGPR_Count=64, WRITE_SIZE=119 MB scratch). This round tests
// named-scalars x big-cap — the only untested cell.

#define LOADQ(QF0, QF1, QG)                                                   \
    do {                                                                      \
        const int qrow_ = qbase + (QG) * 16 + l16;                            \
        const float* qp_ = q + ((size_t)b * SQd + qrow_) * DDIM + quad * 8;   \
        const float4 a0_ = *(const float4*)(qp_);                             \
        const float4 a1_ = *(const float4*)(qp_ + 4);                         \
        const float4 a2_ = *(const float4*)(qp_ + 32);                        \
        const float4 a3_ = *(const float4*)(qp_ + 36);                        \
        int lo_ = pk2<false>(a0_.x * scale, a0_.y * scale, 0);                \
        lo_ = pk2<true>(a0_.z * scale, a0_.w * scale, lo_);                   \
        int hi_ = pk2<false>(a1_.x * scale, a1_.y * scale, 0);                \
        hi_ = pk2<true>(a1_.z * scale, a1_.w * scale, hi_);                   \
        QF0 = mk64(lo_, hi_);                                                 \
        lo_ = pk2<false>(a2_.x * scale, a2_.y * scale, 0);                    \
        lo_ = pk2<true>(a2_.z * scale, a2_.w * scale, lo_);                   \
        hi_ = pk2<false>(a3_.x * scale, a3_.y * scale, 0);                    \
        hi_ = pk2<true>(a3_.z * scale, a3_.w * scale, hi_);                   \
        QF1 = mk64(lo_, hi_);                                                 \
    } while (0)

#define LOADT(T0, T1, T2, T3, t)                                              \
    do {                                                                      \
        const size_t off_ = (size_t)(((t) + phase) & (TPG - 1)) * TILE_BYTES; \
        T0 = *(const int4*)(kg + off_);                                       \
        T1 = *(const int4*)(kg + off_ + 1024);                                \
        T2 = *(const int4*)(vg + off_);                                       \
        T3 = *(const int4*)(vg + off_ + 1024);                                \
    } while (0)

#define QKPV(QF0, QF1, LACC, O0, O1, O2, O3)                                  \
    do {                                                                      \
        floatx4 s0 = sinit, s1 = sinit;                                       \
        s0 = __builtin_amdgcn_mfma_f32_16x16x32_fp8_fp8(k00_, QF0, s0, 0, 0, 0); \
        s0 = __builtin_amdgcn_mfma_f32_16x16x32_fp8_fp8(k01_, QF1, s0, 0, 0, 0); \
        s1 = __builtin_amdgcn_mfma_f32_16x16x32_fp8_fp8(k10_, QF0, s1, 0, 0, 0); \
        s1 = __builtin_amdgcn_mfma_f32_16x16x32_fp8_fp8(k11_, QF1, s1, 0, 0, 0); \
        const float p00 = __builtin_amdgcn_exp2f(s0[0]);                      \
        const float p01 = __builtin_amdgcn_exp2f(s0[1]);                      \
        const float p02 = __builtin_amdgcn_exp2f(s0[2]);                      \
        const float p03 = __builtin_amdgcn_exp2f(s0[3]);                      \
        const float p10 = __builtin_amdgcn_exp2f(s1[0]);                      \
        const float p11 = __builtin_amdgcn_exp2f(s1[1]);                      \
        const float p12 = __builtin_amdgcn_exp2f(s1[2]);                      \
        const float p13 = __builtin_amdgcn_exp2f(s1[3]);                      \
        LACC += (p00 + p01) + (p02 + p03) + (p10 + p11) + (p12 + p13);        \
        int lo_ = pk2<false>(p00, p01, 0); lo_ = pk2<true>(p02, p03, lo_);    \
        int hi_ = pk2<false>(p10, p11, 0); hi_ = pk2<true>(p12, p13, hi_);    \
        const long long pf_ = mk64(lo_, hi_);                                 \
        O0 = __builtin_amdgcn_mfma_f32_16x16x32_fp8_fp8(pf_, v0_, O0, 0, 0, 0); \
        O1 = __builtin_amdgcn_mfma_f32_16x16x32_fp8_fp8(pf_, v1_, O1, 0, 0, 0); \
        O2 = __builtin_amdgcn_mfma_f32_16x16x32_fp8_fp8(pf_, v2_, O2, 0, 0, 0); \
        O3 = __builtin_amdgcn_mfma_f32_16x16x32_fp8_fp8(pf_, v3_, O3, 0, 0, 0); \
    } while (0)

#define STEPC(T0, T1, T2, T3)                                                 \
    do {                                                                      \
        const long long k00_ = mk64((T0).x, (T0).y), k01_ = mk64((T0).z, (T0).w); \
        const long long k10_ = mk64((T1).x, (T1).y), k11_ = mk64((T1).z, (T1).w); \
        const long long v0_ = mk64((T2).x, (T2).y), v1_ = mk64((T2).z, (T2).w);   \
        const long long v2_ = mk64((T3).x, (T3).y), v3_ = mk64((T3).z, (T3).w);   \
        QKPV(qf00, qf01, l0, o00, o01, o02, o03);                             \
        QKPV(qf10, qf11, l1, o10, o11, o12, o13);                             \
    } while (0)

__global__ __launch_bounds__(512, 2)
void fattn_kernel(const float* __restrict__ q, const int* __restrict__ isf_p,
                  const char* __restrict__ kws, const char* __restrict__ vws,
                  float* __restrict__ out)
{
    __shared__ __align__(16) CombS C;

    const int tid  = threadIdx.x;
    const int g    = tid >> 6;    // key group 0..7 (512 keys)
    const int lane = tid & 63;
    const int l16  = lane & 15;
    const int quad = lane >> 4;

    // XCD mapping: b from low bits -> each batch's 1 MB fp8 K/V pinned to 2
    // XCDs' L2; qchunk unique per (b, bidx).
    const int bidx   = blockIdx.x;       // 0..511
    const int b      = (bidx & 7) >> 1;
    const int qchunk = ((bidx & 1) << 6) | (bidx >> 3);   // 0..127
    const int qbase  = qchunk * CROWS;
    const int phase  = (bidx >> 3) & (TPG - 1);

    // exp(s) = 2^(s*log2e); constant -4 folded into the MFMA C-init keeps
    // p' = e^(s-4) within e4m3 range.
    const float scale = 1.44269504088896340736f / (float)(*isf_p);
    const float SINIT = -4.0f * 1.44269504088896340736f;
    const floatx4 sinit = {SINIT, SINIT, SINIT, SINIT};

    long long qf00, qf01, qf10, qf11;
    LOADQ(qf00, qf01, 0);
    LOADQ(qf10, qf11, 1);

    const char* kg = kws + (size_t)(b * NTILES + g * TPG) * TILE_BYTES + lane * 16;
    const char* vg = vws + (size_t)(b * NTILES + g * TPG) * TILE_BYTES + lane * 16;

    floatx4 o00 = {0,0,0,0}, o01 = {0,0,0,0}, o02 = {0,0,0,0}, o03 = {0,0,0,0};
    floatx4 o10 = {0,0,0,0}, o11 = {0,0,0,0}, o12 = {0,0,0,0}, o13 = {0,0,0,0};
    float l0 = 0.0f, l1 = 0.0f;

    // Named double buffer A/B — nothing address-taken, pure registers.
    int4 A0, A1, A2, A3, B0, B1, B2, B3;
    LOADT(A0, A1, A2, A3, 0);
    #pragma unroll
    for (int tt = 0; tt < TPG; tt += 2) {
        LOADT(B0, B1, B2, B3, tt + 1);
        STEPC(A0, A1, A2, A3);
        LOADT(A0, A1, A2, A3, (tt + 2) & (TPG - 1));
        STEPC(B0, B1, B2, B3);
    }

    // Row denominators: lanes sharing l16 (across quads) hold one row.
    l0 += __shfl_xor(l0, 16); l0 += __shfl_xor(l0, 32);
    l1 += __shfl_xor(l1, 16); l1 += __shfl_xor(l1, 32);
    if (quad == 0) {
        C.Lred[l16][g]      = l0;
        C.Lred[16 + l16][g] = l1;
    }

    // Cross-group combine: groups 0-3 write slots, barrier, groups 4-7 add.
    if (g < 4) {
        #pragma unroll
        for (int r = 0; r < 4; ++r) {
            C.Ored[quad * 4 + r][g][l16]      = o00[r];
            C.Ored[quad * 4 + r][g][16 + l16] = o01[r];
            C.Ored[quad * 4 + r][g][32 + l16] = o02[r];
            C.Ored[quad * 4 + r][g][48 + l16] = o03[r];
            C.Ored[16 + quad * 4 + r][g][l16]      = o10[r];
            C.Ored[16 + quad * 4 + r][g][16 + l16] = o11[r];
            C.Ored[16 + quad * 4 + r][g][32 + l16] = o12[r];
            C.Ored[16 + quad * 4 + r][g][48 + l16] = o13[r];
        }
    }
    __syncthreads();
    if (g >= 4) {
        const int gs = g - 4;
        #pragma unroll
        for (int r = 0; r < 4; ++r) {
            C.Ored[quad * 4 + r][gs][l16]      += o00[r];
            C.Ored[quad * 4 + r][gs][16 + l16] += o01[r];
            C.Ored[quad * 4 + r][gs][32 + l16] += o02[r];
            C.Ored[quad * 4 + r][gs][48 + l16] += o03[r];
            C.Ored[16 + quad * 4 + r][gs][l16]      += o10[r];
            C.Ored[16 + quad * 4 + r][gs][16 + l16] += o11[r];
            C.Ored[16 + quad * 4 + r][gs][32 + l16] += o12[r];
            C.Ored[16 + quad * 4 + r][gs][48 + l16] += o13[r];
        }
    }
    __syncthreads();

    // Epilogue: out = attn@v + q; 3x { x += 2q; sigmoid; clamp }.
    {
        const int row = tid >> 4;
        const int d4  = (tid & 15) * 4;
        float l = 0.0f;
        #pragma unroll
        for (int gg = 0; gg < NG; ++gg) l += C.Lred[row][gg];
        const float rl = 1.0f / l;
        float x0 = 0.f, x1 = 0.f, x2 = 0.f, x3 = 0.f;
        #pragma unroll
        for (int s = 0; s < 4; ++s) {
            const float4 t4 = *(const float4*)&C.Ored[row][s][d4];
            x0 += t4.x; x1 += t4.y; x2 += t4.z; x3 += t4.w;
        }
        const size_t idx = ((size_t)b * SQd + qbase + row) * DDIM + d4;
        const float4 q4 = *(const float4*)(q + idx);
        float xs0 = x0 * rl + q4.x, xs1 = x1 * rl + q4.y;
        float xs2 = x2 * rl + q4.z, xs3 = x3 * rl + q4.w;
        #pragma unroll
        for (int itc = 0; itc < 3; ++itc) {
            xs0 = 1.0f / (1.0f + __expf(-(xs0 + 2.0f * q4.x)));
            xs1 = 1.0f / (1.0f + __expf(-(xs1 + 2.0f * q4.y)));
            xs2 = 1.0f / (1.0f + __expf(-(xs2 + 2.0f * q4.z)));
            xs3 = 1.0f / (1.0f + __expf(-(xs3 + 2.0f * q4.w)));
            xs0 = fminf(fmaxf(xs0, 0.0f), 1.0f);
            xs1 = fminf(fmaxf(xs1, 0.0f), 1.0f);
            xs2 = fminf(fmaxf(xs2, 0.0f), 1.0f);
            xs3 = fminf(fmaxf(xs3, 0.0f), 1.0f);
        }
        const float4 r4 = {xs0, xs1, xs2, xs3};
        *(float4*)(out + idx) = r4;
    }
}

extern "C" void kernel_launch(void* const* d_in, const int* in_sizes, int n_in,
                              void* d_out, int out_size, void* d_ws, size_t ws_size,
                              hipStream_t stream) {
    const float* q = (const float*)d_in[0];
    const float* k = (const float*)d_in[1];
    const float* v = (const float*)d_in[2];
    const int* isf = (const int*)d_in[3];
    float* out = (float*)d_out;
    char* ws = (char*)d_ws;   // Kws: 1 MB, Vws: 1 MB (fp8)

    prepack_kernel<<<dim3(4 * NTILES), dim3(256), 0, stream>>>(k, v, ws);

    const int nblocks = 4 * (SQd / CROWS);  // 512 blocks x 512 threads, 2/CU
    fattn_kernel<<<dim3(nblocks), dim3(512), 0, stream>>>(
        q, isf, ws, ws + KWS_BYTES, out);
}